// Round 4
// baseline (483.313 us; speedup 1.0000x reference)
//
#include <hip/hip_runtime.h>
#include <math.h>

#define HD 723.3702371153271f
#define HW2 1048576  // 1024*1024

typedef float float4u __attribute__((ext_vector_type(4), aligned(4)));

__device__ __forceinline__ float lin21(const float* __restrict__ t, float soft) {
    soft = fminf(fmaxf(soft, 0.f), 20.f);
    float fl = floorf(soft);
    int lo = (int)fl;
    int hi = (int)ceilf(soft);
    float f = soft - fl;
    return t[lo] * (1.f - f) + t[hi] * f;
}

// ---------------- K0: relative illumination + transpose to planar (B,C,H,W), 4 px/thread ----------------
__global__ __launch_bounds__(256) void k0_ri(const float* __restrict__ img,
                                             const float* __restrict__ ri_tab,
                                             float* __restrict__ img_ri) {
    int t = blockIdx.x * 256 + threadIdx.x;  // t < 1048576
    int p0 = t * 4;                          // 4 consecutive pixels, same row (W%4==0)
    int b = p0 >> 20;
    int rem = p0 & (HW2 - 1);
    int y = rem >> 10, x = rem & 1023;
    const float4* src = (const float4*)(img + (size_t)p0 * 3);
    float4 A = src[0], Bv = src[1], Cv = src[2];
    float yn = ((float)y - 511.5f) / HD;
    float ri[4];
    #pragma unroll
    for (int k = 0; k < 4; ++k) {
        float xn = ((float)(x + k) - 511.5f) / HD;
        float r = sqrtf(xn * xn + yn * yn);
        ri[k] = lin21(ri_tab, fminf(r, 1.f) * 20.f);
    }
    size_t base = ((size_t)(b * 3) << 20) + (size_t)y * 1024 + x;
    float4 r0 = {A.x * ri[0], A.w * ri[1], Bv.z * ri[2], Cv.y * ri[3]};
    float4 r1 = {A.y * ri[0], Bv.x * ri[1], Bv.w * ri[2], Cv.z * ri[3]};
    float4 r2 = {A.z * ri[0], Bv.y * ri[1], Cv.x * ri[2], Cv.w * ri[3]};
    *(float4*)(img_ri + base) = r0;
    *(float4*)(img_ri + base + HW2) = r1;
    *(float4*)(img_ri + base + 2 * (size_t)HW2) = r2;
}

// ---------------- K1a: per-cell weights (ballot histogram) + 21-tap interp + rotate ----------------
__global__ __launch_bounds__(256) void k1a_rot(const float* __restrict__ spsfs,
                                               float* __restrict__ rot) {
    __shared__ __align__(16) float bufA[65 * 65 * 3];  // 50700 B
    __shared__ int ihist[21];
    __shared__ float wts[21];
    int g = blockIdx.x;
    int gy = g >> 3, gx = g & 7;
    int tid = threadIdx.x;
    if (tid < 21) ihist[tid] = 0;
    __syncthreads();
    // histogram of round(field_map*20) over this 128x128 patch — ballot counting
    int cnt[21];
    #pragma unroll
    for (int f = 0; f < 21; ++f) cnt[f] = 0;
    for (int i = tid; i < 128 * 128; i += 256) {
        int py = i >> 7, px = i & 127;
        int yg = gy * 128 + py, xg = gx * 128 + px;
        float xn = ((float)xg - 511.5f) / HD;
        float yn = ((float)yg - 511.5f) / HD;
        float r = sqrtf(xn * xn + yn * yn);
        int fbin = (int)rintf(fminf(r, 1.f) * 20.f);
        #pragma unroll
        for (int f = 0; f < 21; ++f)
            cnt[f] += __popcll(__ballot(fbin == f));
    }
    if ((tid & 63) == 0) {
        #pragma unroll
        for (int f = 0; f < 21; ++f)
            if (cnt[f] > 0) atomicAdd(&ihist[f], cnt[f]);
    }
    __syncthreads();
    if (tid < 21) wts[tid] = (float)ihist[tid] * (1.f / 16384.f);
    __syncthreads();
    // interp: bufA[i] = sum_f w[f] * spsfs[f][i]
    for (int i = tid; i < 65 * 65 * 3; i += 256) {
        float acc = 0.f;
        #pragma unroll
        for (int f = 0; f < 21; ++f) acc = fmaf(wts[f], spsfs[f * (65 * 65 * 3) + i], acc);
        bufA[i] = acc;
    }
    __syncthreads();
    // rotation by -angle, bilinear, zero outside
    float x0c = -511.5f / HD, span = 1023.0f / HD;
    float xc = ((float)gx + 0.5f) * 0.125f * span + x0c;
    float yc = ((float)gy + 0.5f) * 0.125f * span + x0c;
    float a = -atan2f(xc, yc);
    float ca = cosf(a), sa = sinf(a);
    float* rg = rot + (size_t)g * (65 * 65 * 3);
    for (int i = tid; i < 65 * 65; i += 256) {
        int y = i / 65;
        int x = i - y * 65;
        float dx = (float)x - 32.f, dy = (float)y - 32.f;
        float sx = ca * dx + sa * dy + 32.f;
        float sy = -sa * dx + ca * dy + 32.f;
        float fxf = floorf(sx), fyf = floorf(sy);
        int ix0 = (int)fxf, iy0 = (int)fyf;
        float fx = sx - fxf, fy = sy - fyf;
        float w00 = (1.f - fy) * (1.f - fx);
        float w01 = (1.f - fy) * fx;
        float w10 = fy * (1.f - fx);
        float w11 = fy * fx;
        bool vx0 = (ix0 >= 0) && (ix0 < 65);
        bool vx1 = (ix0 + 1 >= 0) && (ix0 + 1 < 65);
        bool vy0 = (iy0 >= 0) && (iy0 < 65);
        bool vy1 = (iy0 + 1 >= 0) && (iy0 + 1 < 65);
        int cx0 = min(max(ix0, 0), 64), cx1 = min(max(ix0 + 1, 0), 64);
        int cy0 = min(max(iy0, 0), 64), cy1 = min(max(iy0 + 1, 0), 64);
        #pragma unroll
        for (int c = 0; c < 3; ++c) {
            float v00 = (vy0 && vx0) ? bufA[(cy0 * 65 + cx0) * 3 + c] : 0.f;
            float v01 = (vy0 && vx1) ? bufA[(cy0 * 65 + cx1) * 3 + c] : 0.f;
            float v10 = (vy1 && vx0) ? bufA[(cy1 * 65 + cx0) * 3 + c] : 0.f;
            float v11 = (vy1 && vx1) ? bufA[(cy1 * 65 + cx1) * 3 + c] : 0.f;
            rg[i * 3 + c] = w00 * v00 + w01 * v01 + w10 * v10 + w11 * v11;
        }
    }
}

// ---------------- K1b: antialiased linear resize 65->23 (both dims) + normalize ----------------
__global__ __launch_bounds__(256) void k1b_resize(const float* __restrict__ rot,
                                                  float* __restrict__ psfs_out) {
    __shared__ float tmp[65 * 23 * 3];    // after x-resize: [y][ox][c]
    __shared__ float out23[23 * 23 * 3];  // [oy][ox][c]
    __shared__ float csum[3];
    const float INV = 65.f / 23.f;        // inv_scale == kernel_scale (antialias)
    int g = blockIdx.x;
    int tid = threadIdx.x;
    const float* rg = rot + (size_t)g * (65 * 65 * 3);
    // resize along x
    for (int i = tid; i < 65 * 23 * 3; i += 256) {
        int y = i / 69;
        int rem = i - y * 69;
        int ox = rem / 3;
        int c = rem - ox * 3;
        float center = ((float)ox + 0.5f) * INV - 0.5f;
        int ilo = max(0, (int)ceilf(center - INV));
        int ihi = min(64, (int)floorf(center + INV));
        float acc = 0.f, wsum = 0.f;
        for (int ix = ilo; ix <= ihi; ++ix) {
            float w = fmaxf(1.f - fabsf(center - (float)ix) / INV, 0.f);
            acc += w * rg[(y * 65 + ix) * 3 + c];
            wsum += w;
        }
        tmp[i] = acc / wsum;
    }
    __syncthreads();
    // resize along y
    for (int i = tid; i < 23 * 23 * 3; i += 256) {
        int oy = i / 69;
        int rem = i - oy * 69;
        int ox = rem / 3;
        int c = rem - ox * 3;
        float center = ((float)oy + 0.5f) * INV - 0.5f;
        int ilo = max(0, (int)ceilf(center - INV));
        int ihi = min(64, (int)floorf(center + INV));
        float acc = 0.f, wsum = 0.f;
        for (int iy = ilo; iy <= ihi; ++iy) {
            float w = fmaxf(1.f - fabsf(center - (float)iy) / INV, 0.f);
            acc += w * tmp[iy * 69 + ox * 3 + c];
            wsum += w;
        }
        out23[i] = acc / wsum;
    }
    __syncthreads();
    // per-channel sum: one wave per channel, lane-strided partials + shuffle reduce
    if (tid < 192) {
        int c = tid >> 6;
        int l = tid & 63;
        float s = 0.f;
        for (int j = l; j < 529; j += 64) s += out23[j * 3 + c];
        #pragma unroll
        for (int off = 32; off > 0; off >>= 1) s += __shfl_down(s, off);
        if (l == 0) csum[c] = s;
    }
    __syncthreads();
    // write planar per-channel psf: [g][c][ky*23+kx]
    for (int i = tid; i < 23 * 23 * 3; i += 256) {
        int pix = i / 3;
        int c = i - pix * 3;
        psfs_out[((size_t)g * 3 + c) * 529 + pix] = out23[i] / csum[c];
    }
}

// ---------------- K2: depthwise 23x23 conv per patch (SAME, zero-pad within patch) ----------------
// __launch_bounds__(256,2): LDS (33.7KB) caps residency at 4 blocks/CU anyway;
// declaring only 2 waves/SIMD gives the allocator a 256-VGPR budget -> zero spill risk
// for the ~80-float live set (acc16 + line40 + wrow24).
#define LSTRIDE 156
__global__ __launch_bounds__(256, 2) void k2_conv(const float* __restrict__ img_ri,
                                                  const float* __restrict__ psfs,
                                                  float* __restrict__ blurred) {
    __shared__ __align__(16) float s_img[54 * LSTRIDE];  // 33696 B
    __shared__ __align__(16) float s_psf[23 * 24];       // 2208 B
    int ytile = blockIdx.x;  // 0..3
    int g = blockIdx.y;      // 0..63
    int bc = blockIdx.z;     // 0..11 = b*3+c
    int gy = g >> 3, gx = g & 7;
    int c = bc - (bc / 3) * 3;
    int tid = threadIdx.x;
    for (int i = tid; i < 23 * 24; i += 256) {
        int ky = i / 24, kx = i - ky * 24;
        s_psf[i] = (kx < 23) ? psfs[((size_t)g * 3 + c) * 529 + ky * 23 + kx] : 0.f;
    }
    const float* plane = img_ri + (size_t)bc * HW2;
    int py0 = ytile * 32 - 11;  // patch-local first staged row
    for (int i = tid; i < 54 * LSTRIDE; i += 256) {
        int r = i / LSTRIDE;
        int col = i - r * LSTRIDE;
        int py = py0 + r;
        int px = col - 11;
        float v = 0.f;
        if (py >= 0 && py < 128 && px >= 0 && px < 128)
            v = plane[(size_t)(gy * 128 + py) * 1024 + (gx * 128 + px)];
        s_img[i] = v;
    }
    __syncthreads();
    int tx = tid & 7, ty = tid >> 3;  // tx 0..7 (x16 outputs), ty 0..31 (row)
    float acc[16] __attribute__((aligned(16)));
    #pragma unroll
    for (int i = 0; i < 16; ++i) acc[i] = 0.f;
    #pragma unroll 1
    for (int ky = 0; ky < 23; ++ky) {
        float wrow[24] __attribute__((aligned(16)));
        const float4* wr4 = (const float4*)&s_psf[ky * 24];
        #pragma unroll
        for (int j = 0; j < 6; ++j) ((float4*)wrow)[j] = wr4[j];
        float line[40] __attribute__((aligned(16)));
        const float* lrow = &s_img[(ty + ky) * LSTRIDE + tx * 16];
        #pragma unroll
        for (int j = 0; j < 10; ++j) ((float4*)line)[j] = *(const float4*)&lrow[j * 4];
        #pragma unroll
        for (int kx = 0; kx < 23; ++kx) {
            float w = wrow[kx];
            #pragma unroll
            for (int i = 0; i < 16; ++i) acc[i] = fmaf(line[kx + i], w, acc[i]);
        }
    }
    int Y = gy * 128 + ytile * 32 + ty;
    int Xb = gx * 128 + tx * 16;
    float* dst = blurred + (size_t)bc * HW2 + (size_t)Y * 1024 + Xb;
    #pragma unroll
    for (int j = 0; j < 4; ++j) *(float4*)&dst[j * 4] = ((float4*)acc)[j];
}

// ---------------- K3: distortion shift + bicubic warp, planar gather -> (B,H,W,C) ----------------
__device__ __forceinline__ float cub1(float t) { return (1.5f * t - 2.5f) * t * t + 1.f; }
__device__ __forceinline__ float cub2(float t) { return ((-0.5f * t + 2.5f) * t - 4.f) * t + 2.f; }

__global__ __launch_bounds__(256) void k3_warp(const float* __restrict__ blurred,
                                               const float* __restrict__ shifts,
                                               float* __restrict__ out) {
    int p = blockIdx.x * 256 + threadIdx.x;  // p < H*W
    int y = p >> 10, x = p & 1023;
    float xn = ((float)x - 511.5f) / HD;
    float yn = ((float)y - 511.5f) / HD;
    float r = sqrtf(xn * xn + yn * yn);
    float shift = lin21(shifts, r * 20.f);
    float s = shift * HD / r;  // r > 0 everywhere (even H/W)
    float qx = (float)x + s * xn;
    float qy = (float)y + s * yn;
    float fxf = floorf(qx), fyf = floorf(qy);
    int x0 = (int)fxf, y0 = (int)fyf;
    float fx = qx - fxf, fy = qy - fyf;
    float wxx[4] = {cub2(fx + 1.f), cub1(fx), cub1(1.f - fx), cub2(2.f - fx)};
    float wyy[4] = {cub2(fy + 1.f), cub1(fy), cub1(1.f - fy), cub2(2.f - fy)};
    float acc[12];
    #pragma unroll
    for (int q = 0; q < 12; ++q) acc[q] = 0.f;
    bool safe = (x0 >= 1) && (x0 <= 1020);
    if (safe) {
        // fast path: 4 contiguous x-taps -> one unaligned float4 per (row, plane)
        #pragma unroll
        for (int j = 0; j < 4; ++j) {
            int yj = min(max(y0 - 1 + j, 0), 1023);
            const float* rowp = blurred + (size_t)yj * 1024 + (x0 - 1);
            float wj = wyy[j];
            #pragma unroll
            for (int q = 0; q < 12; ++q) {
                float4u v = *(const float4u*)(rowp + (size_t)q * HW2);
                float dot = fmaf(v.x, wxx[0], fmaf(v.y, wxx[1], fmaf(v.z, wxx[2], v.w * wxx[3])));
                acc[q] = fmaf(wj, dot, acc[q]);
            }
        }
    } else {
        #pragma unroll
        for (int j = 0; j < 4; ++j) {
            int yj = min(max(y0 - 1 + j, 0), 1023);
            const float* rowp = blurred + (size_t)yj * 1024;
            #pragma unroll
            for (int i2 = 0; i2 < 4; ++i2) {
                int xi = min(max(x0 - 1 + i2, 0), 1023);
                float w = wyy[j] * wxx[i2];
                #pragma unroll
                for (int q = 0; q < 12; ++q)
                    acc[q] = fmaf(w, rowp[(size_t)q * HW2 + xi], acc[q]);
            }
        }
    }
    #pragma unroll
    for (int b = 0; b < 4; ++b) {
        size_t base = ((size_t)b * HW2 + (size_t)p) * 3;
        out[base] = acc[b * 3];
        out[base + 1] = acc[b * 3 + 1];
        out[base + 2] = acc[b * 3 + 2];
    }
}

extern "C" void kernel_launch(void* const* d_in, const int* in_sizes, int n_in,
                              void* d_out, int out_size, void* d_ws, size_t ws_size,
                              hipStream_t stream) {
    const float* img = (const float*)d_in[0];     // (B,H,W,C) f32
    const float* spsfs = (const float*)d_in[1];   // (21,65,65,3) f32
    const float* shifts = (const float*)d_in[2];  // (21,) f32
    const float* ritab = (const float*)d_in[3];   // (21,) f32
    float* out = (float*)d_out;                   // (B,H,W,C) f32

    char* ws = (char*)d_ws;
    float* psfs = (float*)(ws);                                  // 64*3*529*4   = 406,272 B
    float* rot = (float*)(ws + (size_t)524288);                  // 64*65*65*3*4 = 3,244,800 B
    float* img_ri = (float*)(ws + (size_t)4194304);              // 50,331,648 B
    float* blurred = (float*)(ws + (size_t)4194304 + 50331648);  // 50,331,648 B

    k0_ri<<<4096, 256, 0, stream>>>(img, ritab, img_ri);
    k1a_rot<<<64, 256, 0, stream>>>(spsfs, rot);
    k1b_resize<<<64, 256, 0, stream>>>(rot, psfs);
    k2_conv<<<dim3(4, 64, 12), 256, 0, stream>>>(img_ri, psfs, blurred);
    k3_warp<<<4096, 256, 0, stream>>>(blurred, shifts, out);
}

// Round 9
// 437.751 us; speedup vs baseline: 1.1041x; 1.1041x over previous
//
#include <hip/hip_runtime.h>
#include <math.h>

#define HD 723.3702371153271f
#define HW2 1048576  // 1024*1024

typedef float float4u __attribute__((ext_vector_type(4), aligned(4)));

__device__ __forceinline__ float lin21(const float* __restrict__ t, float soft) {
    soft = fminf(fmaxf(soft, 0.f), 20.f);
    float fl = floorf(soft);
    int lo = (int)fl;
    int hi = (int)ceilf(soft);
    float f = soft - fl;
    return t[lo] * (1.f - f) + t[hi] * f;
}

// ---------------- K0: relative illumination + transpose to planar (B,C,H,W), 4 px/thread ----------------
__global__ __launch_bounds__(256) void k0_ri(const float* __restrict__ img,
                                             const float* __restrict__ ri_tab,
                                             float* __restrict__ img_ri) {
    int t = blockIdx.x * 256 + threadIdx.x;  // t < 1048576
    int p0 = t * 4;                          // 4 consecutive pixels, same row (W%4==0)
    int b = p0 >> 20;
    int rem = p0 & (HW2 - 1);
    int y = rem >> 10, x = rem & 1023;
    const float4* src = (const float4*)(img + (size_t)p0 * 3);
    float4 A = src[0], Bv = src[1], Cv = src[2];
    float yn = ((float)y - 511.5f) / HD;
    float ri[4];
    #pragma unroll
    for (int k = 0; k < 4; ++k) {
        float xn = ((float)(x + k) - 511.5f) / HD;
        float r = sqrtf(xn * xn + yn * yn);
        ri[k] = lin21(ri_tab, fminf(r, 1.f) * 20.f);
    }
    size_t base = ((size_t)(b * 3) << 20) + (size_t)y * 1024 + x;
    float4 r0 = {A.x * ri[0], A.w * ri[1], Bv.z * ri[2], Cv.y * ri[3]};
    float4 r1 = {A.y * ri[0], Bv.x * ri[1], Bv.w * ri[2], Cv.z * ri[3]};
    float4 r2 = {A.z * ri[0], Bv.y * ri[1], Cv.x * ri[2], Cv.w * ri[3]};
    *(float4*)(img_ri + base) = r0;
    *(float4*)(img_ri + base + HW2) = r1;
    *(float4*)(img_ri + base + 2 * (size_t)HW2) = r2;
}

// ---------------- K1a: per-cell weights (ballot histogram) + 21-tap interp + rotate ----------------
__global__ __launch_bounds__(256) void k1a_rot(const float* __restrict__ spsfs,
                                               float* __restrict__ rot) {
    __shared__ __align__(16) float bufA[65 * 65 * 3];  // 50700 B
    __shared__ int ihist[21];
    __shared__ float wts[21];
    int g = blockIdx.x;
    int gy = g >> 3, gx = g & 7;
    int tid = threadIdx.x;
    if (tid < 21) ihist[tid] = 0;
    __syncthreads();
    // histogram of round(field_map*20) over this 128x128 patch — ballot counting
    int cnt[21];
    #pragma unroll
    for (int f = 0; f < 21; ++f) cnt[f] = 0;
    for (int i = tid; i < 128 * 128; i += 256) {
        int py = i >> 7, px = i & 127;
        int yg = gy * 128 + py, xg = gx * 128 + px;
        float xn = ((float)xg - 511.5f) / HD;
        float yn = ((float)yg - 511.5f) / HD;
        float r = sqrtf(xn * xn + yn * yn);
        int fbin = (int)rintf(fminf(r, 1.f) * 20.f);
        #pragma unroll
        for (int f = 0; f < 21; ++f)
            cnt[f] += __popcll(__ballot(fbin == f));
    }
    if ((tid & 63) == 0) {
        #pragma unroll
        for (int f = 0; f < 21; ++f)
            if (cnt[f] > 0) atomicAdd(&ihist[f], cnt[f]);
    }
    __syncthreads();
    if (tid < 21) wts[tid] = (float)ihist[tid] * (1.f / 16384.f);
    __syncthreads();
    // interp: bufA[i] = sum_f w[f] * spsfs[f][i]
    for (int i = tid; i < 65 * 65 * 3; i += 256) {
        float acc = 0.f;
        #pragma unroll
        for (int f = 0; f < 21; ++f) acc = fmaf(wts[f], spsfs[f * (65 * 65 * 3) + i], acc);
        bufA[i] = acc;
    }
    __syncthreads();
    // rotation by -angle, bilinear, zero outside
    float x0c = -511.5f / HD, span = 1023.0f / HD;
    float xc = ((float)gx + 0.5f) * 0.125f * span + x0c;
    float yc = ((float)gy + 0.5f) * 0.125f * span + x0c;
    float a = -atan2f(xc, yc);
    float ca = cosf(a), sa = sinf(a);
    float* rg = rot + (size_t)g * (65 * 65 * 3);
    for (int i = tid; i < 65 * 65; i += 256) {
        int y = i / 65;
        int x = i - y * 65;
        float dx = (float)x - 32.f, dy = (float)y - 32.f;
        float sx = ca * dx + sa * dy + 32.f;
        float sy = -sa * dx + ca * dy + 32.f;
        float fxf = floorf(sx), fyf = floorf(sy);
        int ix0 = (int)fxf, iy0 = (int)fyf;
        float fx = sx - fxf, fy = sy - fyf;
        float w00 = (1.f - fy) * (1.f - fx);
        float w01 = (1.f - fy) * fx;
        float w10 = fy * (1.f - fx);
        float w11 = fy * fx;
        bool vx0 = (ix0 >= 0) && (ix0 < 65);
        bool vx1 = (ix0 + 1 >= 0) && (ix0 + 1 < 65);
        bool vy0 = (iy0 >= 0) && (iy0 < 65);
        bool vy1 = (iy0 + 1 >= 0) && (iy0 + 1 < 65);
        int cx0 = min(max(ix0, 0), 64), cx1 = min(max(ix0 + 1, 0), 64);
        int cy0 = min(max(iy0, 0), 64), cy1 = min(max(iy0 + 1, 0), 64);
        #pragma unroll
        for (int c = 0; c < 3; ++c) {
            float v00 = (vy0 && vx0) ? bufA[(cy0 * 65 + cx0) * 3 + c] : 0.f;
            float v01 = (vy0 && vx1) ? bufA[(cy0 * 65 + cx1) * 3 + c] : 0.f;
            float v10 = (vy1 && vx0) ? bufA[(cy1 * 65 + cx0) * 3 + c] : 0.f;
            float v11 = (vy1 && vx1) ? bufA[(cy1 * 65 + cx1) * 3 + c] : 0.f;
            rg[i * 3 + c] = w00 * v00 + w01 * v01 + w10 * v10 + w11 * v11;
        }
    }
}

// ---------------- K1b: antialiased linear resize 65->23 (both dims) + normalize ----------------
__global__ __launch_bounds__(256) void k1b_resize(const float* __restrict__ rot,
                                                  float* __restrict__ psfs_out) {
    __shared__ float tmp[65 * 23 * 3];    // after x-resize: [y][ox][c]
    __shared__ float out23[23 * 23 * 3];  // [oy][ox][c]
    __shared__ float csum[3];
    const float INV = 65.f / 23.f;        // inv_scale == kernel_scale (antialias)
    int g = blockIdx.x;
    int tid = threadIdx.x;
    const float* rg = rot + (size_t)g * (65 * 65 * 3);
    // resize along x
    for (int i = tid; i < 65 * 23 * 3; i += 256) {
        int y = i / 69;
        int rem = i - y * 69;
        int ox = rem / 3;
        int c = rem - ox * 3;
        float center = ((float)ox + 0.5f) * INV - 0.5f;
        int ilo = max(0, (int)ceilf(center - INV));
        int ihi = min(64, (int)floorf(center + INV));
        float acc = 0.f, wsum = 0.f;
        for (int ix = ilo; ix <= ihi; ++ix) {
            float w = fmaxf(1.f - fabsf(center - (float)ix) / INV, 0.f);
            acc += w * rg[(y * 65 + ix) * 3 + c];
            wsum += w;
        }
        tmp[i] = acc / wsum;
    }
    __syncthreads();
    // resize along y
    for (int i = tid; i < 23 * 23 * 3; i += 256) {
        int oy = i / 69;
        int rem = i - oy * 69;
        int ox = rem / 3;
        int c = rem - ox * 3;
        float center = ((float)oy + 0.5f) * INV - 0.5f;
        int ilo = max(0, (int)ceilf(center - INV));
        int ihi = min(64, (int)floorf(center + INV));
        float acc = 0.f, wsum = 0.f;
        for (int iy = ilo; iy <= ihi; ++iy) {
            float w = fmaxf(1.f - fabsf(center - (float)iy) / INV, 0.f);
            acc += w * tmp[iy * 69 + ox * 3 + c];
            wsum += w;
        }
        out23[i] = acc / wsum;
    }
    __syncthreads();
    // per-channel sum: one wave per channel, lane-strided partials + shuffle reduce
    if (tid < 192) {
        int c = tid >> 6;
        int l = tid & 63;
        float s = 0.f;
        for (int j = l; j < 529; j += 64) s += out23[j * 3 + c];
        #pragma unroll
        for (int off = 32; off > 0; off >>= 1) s += __shfl_down(s, off);
        if (l == 0) csum[c] = s;
    }
    __syncthreads();
    // write planar per-channel psf: [g][c][ky*23+kx]
    for (int i = tid; i < 23 * 23 * 3; i += 256) {
        int pix = i / 3;
        int c = i - pix * 3;
        psfs_out[((size_t)g * 3 + c) * 529 + pix] = out23[i] / csum[c];
    }
}

// ---------------- K2: depthwise 23x23 conv per patch (SAME, zero-pad within patch) ----------------
// LDS XOR swizzle: dword d -> d ^ (((d>>5)&3)<<2)  (byte bits 4-5 ^= byte bits 7-8).
// Makes the 64B-lane-strided ds_read_b128 line loads conflict-free (each quarter-wave
// covers all 32 banks 2-way, which is free). Buffer padded to 8448 dwords (128B multiple)
// so the XOR is in-bounds & bijective. Write (scalar staging) and read use the same map.
#define LSTRIDE 156
#define SWZ(d) ((d) ^ ((((d) >> 5) & 3) << 2))
__global__ __launch_bounds__(256, 2) void k2_conv(const float* __restrict__ img_ri,
                                                  const float* __restrict__ psfs,
                                                  float* __restrict__ blurred) {
    __shared__ __align__(16) float s_img[8448];     // 54*156=8424 dwords, padded -> 33792 B
    __shared__ __align__(16) float s_psf[23 * 24];  // 2208 B
    int ytile = blockIdx.x;  // 0..3
    int g = blockIdx.y;      // 0..63
    int bc = blockIdx.z;     // 0..11 = b*3+c
    int gy = g >> 3, gx = g & 7;
    int c = bc - (bc / 3) * 3;
    int tid = threadIdx.x;
    for (int i = tid; i < 23 * 24; i += 256) {
        int ky = i / 24, kx = i - ky * 24;
        s_psf[i] = (kx < 23) ? psfs[((size_t)g * 3 + c) * 529 + ky * 23 + kx] : 0.f;
    }
    const float* plane = img_ri + (size_t)bc * HW2;
    int py0 = ytile * 32 - 11;  // patch-local first staged row
    for (int i = tid; i < 54 * LSTRIDE; i += 256) {
        int r = i / LSTRIDE;
        int col = i - r * LSTRIDE;
        int py = py0 + r;
        int px = col - 11;
        float v = 0.f;
        if (py >= 0 && py < 128 && px >= 0 && px < 128)
            v = plane[(size_t)(gy * 128 + py) * 1024 + (gx * 128 + px)];
        s_img[SWZ(i)] = v;
    }
    __syncthreads();
    int tx = tid & 7, ty = tid >> 3;  // tx 0..7 (x16 outputs), ty 0..31 (row)
    float acc[16] __attribute__((aligned(16)));
    #pragma unroll
    for (int i = 0; i < 16; ++i) acc[i] = 0.f;
    #pragma unroll 1
    for (int ky = 0; ky < 23; ++ky) {
        float wrow[24] __attribute__((aligned(16)));
        const float4* wr4 = (const float4*)&s_psf[ky * 24];
        #pragma unroll
        for (int j = 0; j < 6; ++j) ((float4*)wrow)[j] = wr4[j];
        float line[40] __attribute__((aligned(16)));
        int rowbase = (ty + ky) * LSTRIDE + tx * 16;
        #pragma unroll
        for (int j = 0; j < 10; ++j) {
            int d = rowbase + j * 4;
            ((float4*)line)[j] = *(const float4*)&s_img[SWZ(d)];
        }
        #pragma unroll
        for (int kx = 0; kx < 23; ++kx) {
            float w = wrow[kx];
            #pragma unroll
            for (int i = 0; i < 16; ++i) acc[i] = fmaf(line[kx + i], w, acc[i]);
        }
    }
    int Y = gy * 128 + ytile * 32 + ty;
    int Xb = gx * 128 + tx * 16;
    float* dst = blurred + (size_t)bc * HW2 + (size_t)Y * 1024 + Xb;
    #pragma unroll
    for (int j = 0; j < 4; ++j) *(float4*)&dst[j * 4] = ((float4*)acc)[j];
}

// ---------------- K3: distortion shift + bicubic warp, planar gather -> (B,H,W,C) ----------------
__device__ __forceinline__ float cub1(float t) { return (1.5f * t - 2.5f) * t * t + 1.f; }
__device__ __forceinline__ float cub2(float t) { return ((-0.5f * t + 2.5f) * t - 4.f) * t + 2.f; }

__global__ __launch_bounds__(256) void k3_warp(const float* __restrict__ blurred,
                                               const float* __restrict__ shifts,
                                               float* __restrict__ out) {
    int p = blockIdx.x * 256 + threadIdx.x;  // p < H*W
    int y = p >> 10, x = p & 1023;
    float xn = ((float)x - 511.5f) / HD;
    float yn = ((float)y - 511.5f) / HD;
    float r = sqrtf(xn * xn + yn * yn);
    float shift = lin21(shifts, r * 20.f);
    float s = shift * HD / r;  // r > 0 everywhere (even H/W)
    float qx = (float)x + s * xn;
    float qy = (float)y + s * yn;
    float fxf = floorf(qx), fyf = floorf(qy);
    int x0 = (int)fxf, y0 = (int)fyf;
    float fx = qx - fxf, fy = qy - fyf;
    float wxx[4] = {cub2(fx + 1.f), cub1(fx), cub1(1.f - fx), cub2(2.f - fx)};
    float wyy[4] = {cub2(fy + 1.f), cub1(fy), cub1(1.f - fy), cub2(2.f - fy)};
    float acc[12];
    #pragma unroll
    for (int q = 0; q < 12; ++q) acc[q] = 0.f;
    bool safe = (x0 >= 1) && (x0 <= 1020);
    if (safe) {
        // fast path: 4 contiguous x-taps -> one unaligned float4 per (row, plane)
        #pragma unroll
        for (int j = 0; j < 4; ++j) {
            int yj = min(max(y0 - 1 + j, 0), 1023);
            const float* rowp = blurred + (size_t)yj * 1024 + (x0 - 1);
            float wj = wyy[j];
            #pragma unroll
            for (int q = 0; q < 12; ++q) {
                float4u v = *(const float4u*)(rowp + (size_t)q * HW2);
                float dot = fmaf(v.x, wxx[0], fmaf(v.y, wxx[1], fmaf(v.z, wxx[2], v.w * wxx[3])));
                acc[q] = fmaf(wj, dot, acc[q]);
            }
        }
    } else {
        #pragma unroll
        for (int j = 0; j < 4; ++j) {
            int yj = min(max(y0 - 1 + j, 0), 1023);
            const float* rowp = blurred + (size_t)yj * 1024;
            #pragma unroll
            for (int i2 = 0; i2 < 4; ++i2) {
                int xi = min(max(x0 - 1 + i2, 0), 1023);
                float w = wyy[j] * wxx[i2];
                #pragma unroll
                for (int q = 0; q < 12; ++q)
                    acc[q] = fmaf(w, rowp[(size_t)q * HW2 + xi], acc[q]);
            }
        }
    }
    #pragma unroll
    for (int b = 0; b < 4; ++b) {
        size_t base = ((size_t)b * HW2 + (size_t)p) * 3;
        out[base] = acc[b * 3];
        out[base + 1] = acc[b * 3 + 1];
        out[base + 2] = acc[b * 3 + 2];
    }
}

extern "C" void kernel_launch(void* const* d_in, const int* in_sizes, int n_in,
                              void* d_out, int out_size, void* d_ws, size_t ws_size,
                              hipStream_t stream) {
    const float* img = (const float*)d_in[0];     // (B,H,W,C) f32
    const float* spsfs = (const float*)d_in[1];   // (21,65,65,3) f32
    const float* shifts = (const float*)d_in[2];  // (21,) f32
    const float* ritab = (const float*)d_in[3];   // (21,) f32
    float* out = (float*)d_out;                   // (B,H,W,C) f32

    char* ws = (char*)d_ws;
    float* psfs = (float*)(ws);                                  // 64*3*529*4   = 406,272 B
    float* rot = (float*)(ws + (size_t)524288);                  // 64*65*65*3*4 = 3,244,800 B
    float* img_ri = (float*)(ws + (size_t)4194304);              // 50,331,648 B
    float* blurred = (float*)(ws + (size_t)4194304 + 50331648);  // 50,331,648 B

    k0_ri<<<4096, 256, 0, stream>>>(img, ritab, img_ri);
    k1a_rot<<<64, 256, 0, stream>>>(spsfs, rot);
    k1b_resize<<<64, 256, 0, stream>>>(rot, psfs);
    k2_conv<<<dim3(4, 64, 12), 256, 0, stream>>>(img_ri, psfs, blurred);
    k3_warp<<<4096, 256, 0, stream>>>(blurred, shifts, out);
}

// Round 12
// 432.825 us; speedup vs baseline: 1.1166x; 1.0114x over previous
//
#include <hip/hip_runtime.h>
#include <math.h>

#define HD 723.3702371153271f
#define HW2 1048576  // 1024*1024

typedef float float4u __attribute__((ext_vector_type(4), aligned(4)));

__device__ __forceinline__ float lin21(const float* __restrict__ t, float soft) {
    soft = fminf(fmaxf(soft, 0.f), 20.f);
    float fl = floorf(soft);
    int lo = (int)fl;
    int hi = (int)ceilf(soft);
    float f = soft - fl;
    return t[lo] * (1.f - f) + t[hi] * f;
}

// ---------------- K1a: per-cell weights (ballot histogram) + 21-tap interp + rotate ----------------
__global__ __launch_bounds__(256) void k1a_rot(const float* __restrict__ spsfs,
                                               float* __restrict__ rot) {
    __shared__ __align__(16) float bufA[65 * 65 * 3];  // 50700 B
    __shared__ int ihist[21];
    __shared__ float wts[21];
    int g = blockIdx.x;
    int gy = g >> 3, gx = g & 7;
    int tid = threadIdx.x;
    if (tid < 21) ihist[tid] = 0;
    __syncthreads();
    // histogram of round(field_map*20) over this 128x128 patch — ballot counting
    int cnt[21];
    #pragma unroll
    for (int f = 0; f < 21; ++f) cnt[f] = 0;
    for (int i = tid; i < 128 * 128; i += 256) {
        int py = i >> 7, px = i & 127;
        int yg = gy * 128 + py, xg = gx * 128 + px;
        float xn = ((float)xg - 511.5f) / HD;
        float yn = ((float)yg - 511.5f) / HD;
        float r = sqrtf(xn * xn + yn * yn);
        int fbin = (int)rintf(fminf(r, 1.f) * 20.f);
        #pragma unroll
        for (int f = 0; f < 21; ++f)
            cnt[f] += __popcll(__ballot(fbin == f));
    }
    if ((tid & 63) == 0) {
        #pragma unroll
        for (int f = 0; f < 21; ++f)
            if (cnt[f] > 0) atomicAdd(&ihist[f], cnt[f]);
    }
    __syncthreads();
    if (tid < 21) wts[tid] = (float)ihist[tid] * (1.f / 16384.f);
    __syncthreads();
    // interp: bufA[i] = sum_f w[f] * spsfs[f][i]
    for (int i = tid; i < 65 * 65 * 3; i += 256) {
        float acc = 0.f;
        #pragma unroll
        for (int f = 0; f < 21; ++f) acc = fmaf(wts[f], spsfs[f * (65 * 65 * 3) + i], acc);
        bufA[i] = acc;
    }
    __syncthreads();
    // rotation by -angle, bilinear, zero outside
    float x0c = -511.5f / HD, span = 1023.0f / HD;
    float xc = ((float)gx + 0.5f) * 0.125f * span + x0c;
    float yc = ((float)gy + 0.5f) * 0.125f * span + x0c;
    float a = -atan2f(xc, yc);
    float ca = cosf(a), sa = sinf(a);
    float* rg = rot + (size_t)g * (65 * 65 * 3);
    for (int i = tid; i < 65 * 65; i += 256) {
        int y = i / 65;
        int x = i - y * 65;
        float dx = (float)x - 32.f, dy = (float)y - 32.f;
        float sx = ca * dx + sa * dy + 32.f;
        float sy = -sa * dx + ca * dy + 32.f;
        float fxf = floorf(sx), fyf = floorf(sy);
        int ix0 = (int)fxf, iy0 = (int)fyf;
        float fx = sx - fxf, fy = sy - fyf;
        float w00 = (1.f - fy) * (1.f - fx);
        float w01 = (1.f - fy) * fx;
        float w10 = fy * (1.f - fx);
        float w11 = fy * fx;
        bool vx0 = (ix0 >= 0) && (ix0 < 65);
        bool vx1 = (ix0 + 1 >= 0) && (ix0 + 1 < 65);
        bool vy0 = (iy0 >= 0) && (iy0 < 65);
        bool vy1 = (iy0 + 1 >= 0) && (iy0 + 1 < 65);
        int cx0 = min(max(ix0, 0), 64), cx1 = min(max(ix0 + 1, 0), 64);
        int cy0 = min(max(iy0, 0), 64), cy1 = min(max(iy0 + 1, 0), 64);
        #pragma unroll
        for (int c = 0; c < 3; ++c) {
            float v00 = (vy0 && vx0) ? bufA[(cy0 * 65 + cx0) * 3 + c] : 0.f;
            float v01 = (vy0 && vx1) ? bufA[(cy0 * 65 + cx1) * 3 + c] : 0.f;
            float v10 = (vy1 && vx0) ? bufA[(cy1 * 65 + cx0) * 3 + c] : 0.f;
            float v11 = (vy1 && vx1) ? bufA[(cy1 * 65 + cx1) * 3 + c] : 0.f;
            rg[i * 3 + c] = w00 * v00 + w01 * v01 + w10 * v10 + w11 * v11;
        }
    }
}

// ---------------- K1b: antialiased linear resize 65->23 (both dims) + normalize ----------------
__global__ __launch_bounds__(256) void k1b_resize(const float* __restrict__ rot,
                                                  float* __restrict__ psfs_out) {
    __shared__ float tmp[65 * 23 * 3];    // after x-resize: [y][ox][c]
    __shared__ float out23[23 * 23 * 3];  // [oy][ox][c]
    __shared__ float csum[3];
    const float INV = 65.f / 23.f;        // inv_scale == kernel_scale (antialias)
    int g = blockIdx.x;
    int tid = threadIdx.x;
    const float* rg = rot + (size_t)g * (65 * 65 * 3);
    // resize along x
    for (int i = tid; i < 65 * 23 * 3; i += 256) {
        int y = i / 69;
        int rem = i - y * 69;
        int ox = rem / 3;
        int c = rem - ox * 3;
        float center = ((float)ox + 0.5f) * INV - 0.5f;
        int ilo = max(0, (int)ceilf(center - INV));
        int ihi = min(64, (int)floorf(center + INV));
        float acc = 0.f, wsum = 0.f;
        for (int ix = ilo; ix <= ihi; ++ix) {
            float w = fmaxf(1.f - fabsf(center - (float)ix) / INV, 0.f);
            acc += w * rg[(y * 65 + ix) * 3 + c];
            wsum += w;
        }
        tmp[i] = acc / wsum;
    }
    __syncthreads();
    // resize along y
    for (int i = tid; i < 23 * 23 * 3; i += 256) {
        int oy = i / 69;
        int rem = i - oy * 69;
        int ox = rem / 3;
        int c = rem - ox * 3;
        float center = ((float)oy + 0.5f) * INV - 0.5f;
        int ilo = max(0, (int)ceilf(center - INV));
        int ihi = min(64, (int)floorf(center + INV));
        float acc = 0.f, wsum = 0.f;
        for (int iy = ilo; iy <= ihi; ++iy) {
            float w = fmaxf(1.f - fabsf(center - (float)iy) / INV, 0.f);
            acc += w * tmp[iy * 69 + ox * 3 + c];
            wsum += w;
        }
        out23[i] = acc / wsum;
    }
    __syncthreads();
    // per-channel sum: one wave per channel, lane-strided partials + shuffle reduce
    if (tid < 192) {
        int c = tid >> 6;
        int l = tid & 63;
        float s = 0.f;
        for (int j = l; j < 529; j += 64) s += out23[j * 3 + c];
        #pragma unroll
        for (int off = 32; off > 0; off >>= 1) s += __shfl_down(s, off);
        if (l == 0) csum[c] = s;
    }
    __syncthreads();
    // write planar per-channel psf: [g][c][ky*23+kx]
    for (int i = tid; i < 23 * 23 * 3; i += 256) {
        int pix = i / 3;
        int c = i - pix * 3;
        psfs_out[((size_t)g * 3 + c) * 529 + pix] = out23[i] / csum[c];
    }
}

// ---------------- K2: RI (fused) + depthwise 23x23 conv per patch (SAME zero-pad in patch) ----------------
// Lane remap vs R9: ty = tid&31 (row), tx = tid>>5 (x-chunk). Consecutive 8 lanes now read 8
// DISTINCT 4-bank spans (row stride 156 ≡ 28 mod 32, full cycle over 8 rows) with plain linear
// addressing — no XOR swizzle, no per-load address math (ds_read imm offsets). A/B vs R9's
// swizzle isolates the HW b128 conflict-grouping model via SQ_LDS_BANK_CONFLICT.
// RI is computed inline during staging (k0 eliminated): identical fp32 op order as the old k0.
#define LSTRIDE 156
__global__ __launch_bounds__(256, 2) void k2_conv(const float* __restrict__ img,
                                                  const float* __restrict__ ri_tab,
                                                  const float* __restrict__ psfs,
                                                  float* __restrict__ blurred) {
    __shared__ __align__(16) float s_img[54 * LSTRIDE];  // 33696 B
    __shared__ __align__(16) float s_psf[23 * 24];       // 2208 B
    int ytile = blockIdx.x;  // 0..3
    int g = blockIdx.y;      // 0..63
    int bc = blockIdx.z;     // 0..11 = b*3+c
    int gy = g >> 3, gx = g & 7;
    int b = bc / 3;
    int c = bc - b * 3;
    int tid = threadIdx.x;
    for (int i = tid; i < 23 * 24; i += 256) {
        int ky = i / 24, kx = i - ky * 24;
        s_psf[i] = (kx < 23) ? psfs[((size_t)g * 3 + c) * 529 + ky * 23 + kx] : 0.f;
    }
    const float* bimg = img + (size_t)b * (3 * (size_t)HW2);
    int py0 = ytile * 32 - 11;  // patch-local first staged row
    for (int i = tid; i < 54 * LSTRIDE; i += 256) {
        int r = i / LSTRIDE;
        int col = i - r * LSTRIDE;
        int py = py0 + r;
        int px = col - 11;
        float v = 0.f;
        if (py >= 0 && py < 128 && px >= 0 && px < 128) {
            int yg = gy * 128 + py, xg = gx * 128 + px;
            float xn = ((float)xg - 511.5f) / HD;
            float yn = ((float)yg - 511.5f) / HD;
            float rr = sqrtf(xn * xn + yn * yn);
            float ri = lin21(ri_tab, fminf(rr, 1.f) * 20.f);
            v = bimg[((size_t)yg * 1024 + xg) * 3 + c] * ri;
        }
        s_img[i] = v;
    }
    __syncthreads();
    int ty = tid & 31, tx = tid >> 5;  // ty 0..31 (row), tx 0..7 (x16 outputs)
    float acc[16] __attribute__((aligned(16)));
    #pragma unroll
    for (int i = 0; i < 16; ++i) acc[i] = 0.f;
    #pragma unroll 1
    for (int ky = 0; ky < 23; ++ky) {
        float wrow[24] __attribute__((aligned(16)));
        const float4* wr4 = (const float4*)&s_psf[ky * 24];
        #pragma unroll
        for (int j = 0; j < 6; ++j) ((float4*)wrow)[j] = wr4[j];
        float line[40] __attribute__((aligned(16)));
        const float* lrow = &s_img[(ty + ky) * LSTRIDE + tx * 16];
        #pragma unroll
        for (int j = 0; j < 10; ++j) ((float4*)line)[j] = *(const float4*)&lrow[j * 4];
        #pragma unroll
        for (int kx = 0; kx < 23; ++kx) {
            float w = wrow[kx];
            #pragma unroll
            for (int i = 0; i < 16; ++i) acc[i] = fmaf(line[kx + i], w, acc[i]);
        }
    }
    int Y = gy * 128 + ytile * 32 + ty;
    int Xb = gx * 128 + tx * 16;
    float* dst = blurred + (size_t)bc * HW2 + (size_t)Y * 1024 + Xb;
    #pragma unroll
    for (int j = 0; j < 4; ++j) *(float4*)&dst[j * 4] = ((float4*)acc)[j];
}

// ---------------- K3: distortion shift + bicubic warp, planar gather -> (B,H,W,C) ----------------
__device__ __forceinline__ float cub1(float t) { return (1.5f * t - 2.5f) * t * t + 1.f; }
__device__ __forceinline__ float cub2(float t) { return ((-0.5f * t + 2.5f) * t - 4.f) * t + 2.f; }

__global__ __launch_bounds__(256) void k3_warp(const float* __restrict__ blurred,
                                               const float* __restrict__ shifts,
                                               float* __restrict__ out) {
    int p = blockIdx.x * 256 + threadIdx.x;  // p < H*W
    int y = p >> 10, x = p & 1023;
    float xn = ((float)x - 511.5f) / HD;
    float yn = ((float)y - 511.5f) / HD;
    float r = sqrtf(xn * xn + yn * yn);
    float shift = lin21(shifts, r * 20.f);
    float s = shift * HD / r;  // r > 0 everywhere (even H/W)
    float qx = (float)x + s * xn;
    float qy = (float)y + s * yn;
    float fxf = floorf(qx), fyf = floorf(qy);
    int x0 = (int)fxf, y0 = (int)fyf;
    float fx = qx - fxf, fy = qy - fyf;
    float wxx[4] = {cub2(fx + 1.f), cub1(fx), cub1(1.f - fx), cub2(2.f - fx)};
    float wyy[4] = {cub2(fy + 1.f), cub1(fy), cub1(1.f - fy), cub2(2.f - fy)};
    float acc[12];
    #pragma unroll
    for (int q = 0; q < 12; ++q) acc[q] = 0.f;
    bool safe = (x0 >= 1) && (x0 <= 1020);
    if (safe) {
        // fast path: 4 contiguous x-taps -> one unaligned float4 per (row, plane)
        #pragma unroll
        for (int j = 0; j < 4; ++j) {
            int yj = min(max(y0 - 1 + j, 0), 1023);
            const float* rowp = blurred + (size_t)yj * 1024 + (x0 - 1);
            float wj = wyy[j];
            #pragma unroll
            for (int q = 0; q < 12; ++q) {
                float4u v = *(const float4u*)(rowp + (size_t)q * HW2);
                float dot = fmaf(v.x, wxx[0], fmaf(v.y, wxx[1], fmaf(v.z, wxx[2], v.w * wxx[3])));
                acc[q] = fmaf(wj, dot, acc[q]);
            }
        }
    } else {
        #pragma unroll
        for (int j = 0; j < 4; ++j) {
            int yj = min(max(y0 - 1 + j, 0), 1023);
            const float* rowp = blurred + (size_t)yj * 1024;
            #pragma unroll
            for (int i2 = 0; i2 < 4; ++i2) {
                int xi = min(max(x0 - 1 + i2, 0), 1023);
                float w = wyy[j] * wxx[i2];
                #pragma unroll
                for (int q = 0; q < 12; ++q)
                    acc[q] = fmaf(w, rowp[(size_t)q * HW2 + xi], acc[q]);
            }
        }
    }
    #pragma unroll
    for (int b = 0; b < 4; ++b) {
        size_t base = ((size_t)b * HW2 + (size_t)p) * 3;
        out[base] = acc[b * 3];
        out[base + 1] = acc[b * 3 + 1];
        out[base + 2] = acc[b * 3 + 2];
    }
}

extern "C" void kernel_launch(void* const* d_in, const int* in_sizes, int n_in,
                              void* d_out, int out_size, void* d_ws, size_t ws_size,
                              hipStream_t stream) {
    const float* img = (const float*)d_in[0];     // (B,H,W,C) f32
    const float* spsfs = (const float*)d_in[1];   // (21,65,65,3) f32
    const float* shifts = (const float*)d_in[2];  // (21,) f32
    const float* ritab = (const float*)d_in[3];   // (21,) f32
    float* out = (float*)d_out;                   // (B,H,W,C) f32

    char* ws = (char*)d_ws;
    float* psfs = (float*)(ws);                      // 64*3*529*4   = 406,272 B
    float* rot = (float*)(ws + (size_t)524288);      // 64*65*65*3*4 = 3,244,800 B
    float* blurred = (float*)(ws + (size_t)4194304); // 50,331,648 B

    k1a_rot<<<64, 256, 0, stream>>>(spsfs, rot);
    k1b_resize<<<64, 256, 0, stream>>>(rot, psfs);
    k2_conv<<<dim3(4, 64, 12), 256, 0, stream>>>(img, ritab, psfs, blurred);
    k3_warp<<<4096, 256, 0, stream>>>(blurred, shifts, out);
}